// Round 1
// baseline (831.220 us; speedup 1.0000x reference)
//
#include <hip/hip_runtime.h>

// CTC total-score forward (log-semiring), B=32 T=800 C=5000 L=100, S=201.
// Outputs: [tot_score, tot_frames, all_frames] as float32.

constexpr int B = 32;
constexpr int T = 800;
constexpr int C = 5000;
constexpr int L = 100;
constexpr int S = 2 * L + 1;   // 201
constexpr int SP = 204;        // padded emit row length (floats); 816 B, 16B-aligned rows
constexpr float NEGV = -1e30f;

// ---------------------------------------------------------------------------
// Kernel 1: emit[b,t,s] = log_probs[b,t,ext[s]]  (ext: even s -> blank(0),
// odd s -> targets[b, s>>1]). One block per (t,b); only rows t < il[b] needed.
// ---------------------------------------------------------------------------
__global__ __launch_bounds__(256) void gather_emit(
    const float* __restrict__ lp, const int* __restrict__ targets,
    const int* __restrict__ il, float* __restrict__ emit)
{
    const int t = blockIdx.x;
    const int b = blockIdx.y;
    if (t >= il[b]) return;              // rows past input_length are never read
    const int s = threadIdx.x;
    if (s >= S) return;
    const int cls = (s & 1) ? targets[b * L + (s >> 1)] : 0;
    const size_t row = (size_t)(b * T + t);
    emit[row * SP + s] = lp[row * C + cls];
}

// ---------------------------------------------------------------------------
// Kernel 2: alpha recursion. One block (= one wave, 64 lanes) per batch item.
// Lane i holds states 4i..4i+3 in registers. Neighbor states via __shfl_up.
// Emit row for t+1 is prefetched during step t.
// ---------------------------------------------------------------------------
__global__ __launch_bounds__(64) void ctc_alpha(
    const float* __restrict__ emit, const int* __restrict__ targets,
    const int* __restrict__ il_, const int* __restrict__ tl_,
    float* __restrict__ out)
{
    const int b    = blockIdx.x;
    const int lane = threadIdx.x;
    const int il   = il_[b];
    const int tl   = tl_[b];
    const float* erow = emit + (size_t)b * T * SP;
    const int s0 = lane * 4;

    // skip_ok per state: odd s with targets[s>>1] != targets[(s>>1)-1] (s==1: true)
    bool skip[4];
#pragma unroll
    for (int j = 0; j < 4; ++j) {
        const int s = s0 + j;
        bool sk = false;
        if ((s & 1) && s < S) {
            const int cur  = targets[b * L + (s >> 1)];
            const int prev = (s >= 3) ? targets[b * L + (s >> 1) - 1] : -1;
            sk = (cur != prev);
        }
        skip[j] = sk;
    }

    // init alpha0: states 0,1 get emit[t=0], rest NEG
    float4 e0 = make_float4(NEGV, NEGV, NEGV, NEGV);
    if (s0 < S) e0 = *(const float4*)(erow + s0);
    float a[4];
    a[0] = (s0 == 0) ? e0.x : NEGV;
    a[1] = (s0 == 0) ? e0.y : NEGV;
    a[2] = NEGV;
    a[3] = NEGV;

    // prefetch t=1
    float4 pref = make_float4(NEGV, NEGV, NEGV, NEGV);
    if (il > 1 && s0 < S) pref = *(const float4*)(erow + (size_t)SP + s0);

    for (int t = 1; t < il; ++t) {
        const float4 e = pref;
        const int tn = (t + 1 < il) ? (t + 1) : t;
        if (s0 < S) pref = *(const float4*)(erow + (size_t)SP * tn + s0);

        float up_a3 = __shfl_up(a[3], 1);   // state 4i-1 (from lane i-1)
        float up_a2 = __shfl_up(a[2], 1);   // state 4i-2
        if (lane == 0) { up_a3 = NEGV; up_a2 = NEGV; }

        const float em[4]   = { e.x, e.y, e.z, e.w };
        const float a2in[4] = { up_a3, a[0], a[1], a[2] };   // alpha[s-1]
        const float a3in[4] = { up_a2, up_a3, a[0], a[1] };  // alpha[s-2]
        float na[4];
#pragma unroll
        for (int j = 0; j < 4; ++j) {
            const float a1 = a[j];
            const float a2 = a2in[j];
            const float a3 = skip[j] ? a3in[j] : NEGV;
            const float m  = fmaxf(a1, fmaxf(a2, a3));
            const float sum = __expf(a1 - m) + __expf(a2 - m) + __expf(a3 - m);
            na[j] = m + __logf(sum) + em[j];
        }
        a[0] = na[0]; a[1] = na[1]; a[2] = na[2]; a[3] = na[3];
    }

    // extract final states 2*tl and 2*tl-1 via LDS
    __shared__ float sm[256];
    sm[s0 + 0] = a[0];
    sm[s0 + 1] = a[1];
    sm[s0 + 2] = a[2];
    sm[s0 + 3] = a[3];
    __syncthreads();

    if (lane == 0) {
        const float va = sm[2 * tl];
        const float vb = sm[2 * tl - 1];
        const float m  = fmaxf(va, vb);
        const float tot = m + __logf(__expf(va - m) + __expf(vb - m));
        const bool finite = tot > (NEGV * 0.5f);
        atomicAdd(out + 0, finite ? tot : 0.0f);
        atomicAdd(out + 1, finite ? (float)il : 0.0f);
        atomicAdd(out + 2, (float)il);
    }
}

extern "C" void kernel_launch(void* const* d_in, const int* in_sizes, int n_in,
                              void* d_out, int out_size, void* d_ws, size_t ws_size,
                              hipStream_t stream)
{
    const float* lp      = (const float*)d_in[0];   // (B,T,C) f32
    const int*   targets = (const int*)d_in[1];     // (B,L)
    const int*   il      = (const int*)d_in[2];     // (B,)
    const int*   tl      = (const int*)d_in[3];     // (B,)
    float* out  = (float*)d_out;                    // 3 floats
    float* emit = (float*)d_ws;                     // B*T*SP floats = ~20.9 MB

    hipMemsetAsync(d_out, 0, (size_t)out_size * sizeof(float), stream);

    dim3 g1(T, B);
    gather_emit<<<g1, 256, 0, stream>>>(lp, targets, il, emit);
    ctc_alpha<<<B, 64, 0, stream>>>(emit, targets, il, tl, out);
}